// Round 1
// baseline (365.099 us; speedup 1.0000x reference)
//
#include <hip/hip_runtime.h>
#include <math.h>

#define B_ 8
#define N_ 1024
#define C_ 256
#define H_ 4
#define D_ 64
#define CN_ 256
#define EPS_ 1e-6f

// ---------------- threefry2x32 (JAX-compatible) ----------------
__device__ __forceinline__ unsigned rotl32(unsigned x, int r){ return (x<<r)|(x>>(32-r)); }

__device__ float tf_noise(unsigned gid){
  // jax.random.uniform(key(42), (8,1024)): threefry2x32 key (0,42) over iota(8192)
  // split: pair (i, i+4096); out = concat(final_x0, final_x1)
  unsigned c0 = (gid >= 4096u) ? gid - 4096u : gid;
  unsigned c1 = c0 + 4096u;
  const unsigned k0 = 0u, k1 = 42u;
  const unsigned ks2 = k0 ^ k1 ^ 0x1BD11BDAu;
  unsigned x0 = c0 + k0, x1 = c1 + k1;
  const int R0[4] = {13,15,26,6};
  const int R1[4] = {17,29,16,24};
  #pragma unroll
  for (int i=0;i<4;i++){ x0 += x1; x1 = rotl32(x1,R0[i]); x1 ^= x0; }
  x0 += k1; x1 += ks2 + 1u;
  #pragma unroll
  for (int i=0;i<4;i++){ x0 += x1; x1 = rotl32(x1,R1[i]); x1 ^= x0; }
  x0 += ks2; x1 += k0 + 2u;
  #pragma unroll
  for (int i=0;i<4;i++){ x0 += x1; x1 = rotl32(x1,R0[i]); x1 ^= x0; }
  x0 += k0; x1 += k1 + 3u;
  #pragma unroll
  for (int i=0;i<4;i++){ x0 += x1; x1 = rotl32(x1,R1[i]); x1 ^= x0; }
  x0 += k1; x1 += ks2 + 4u;
  #pragma unroll
  for (int i=0;i<4;i++){ x0 += x1; x1 = rotl32(x1,R0[i]); x1 ^= x0; }
  x0 += ks2; x1 += k0 + 5u;
  unsigned bits = (gid >= 4096u) ? x1 : x0;
  return __uint_as_float(0x3F800000u | (bits >> 9)) - 1.0f;
}

// ---------------- sq of rows ----------------
__global__ __launch_bounds__(256) void k_sq(const float* __restrict__ x, float* __restrict__ sq){
  int row = blockIdx.x * 4 + (threadIdx.x >> 6);
  int l = threadIdx.x & 63;
  const float* p = x + (size_t)row * C_;
  float s = 0.f;
  #pragma unroll
  for (int t=0;t<4;t++){ float v = p[l + 64*t]; s += v*v; }
  #pragma unroll
  for (int m=32;m;m>>=1) s += __shfl_xor(s, m);
  if (l==0) sq[row] = s;
}

// ---------------- dist = sqrt(max(sq_i+sq_j-2*x.x^T,0))/16 ----------------
__global__ __launch_bounds__(256) void k_dist(const float* __restrict__ x, const float* __restrict__ sq,
                                              float* __restrict__ dist){
  int b = blockIdx.z;
  int bi = blockIdx.y, bj = blockIdx.x;
  const float* xb = x + (size_t)b * N_ * C_;
  __shared__ __align__(16) float As[32][68];
  __shared__ __align__(16) float Bs[32][68];
  int tid = threadIdx.x;
  int tx = tid & 15, ty = tid >> 4;
  int lrow = tid >> 3, lk = (tid & 7)*4;
  float acc[4][4] = {};
  for (int k0=0;k0<C_;k0+=32){
    #pragma unroll
    for (int rr=0;rr<2;rr++){
      int r = rr*32 + lrow;
      float4 a = *(const float4*)(xb + (size_t)(bi*64 + r)*C_ + k0 + lk);
      As[lk+0][r]=a.x; As[lk+1][r]=a.y; As[lk+2][r]=a.z; As[lk+3][r]=a.w;
      float4 c = *(const float4*)(xb + (size_t)(bj*64 + r)*C_ + k0 + lk);
      Bs[lk+0][r]=c.x; Bs[lk+1][r]=c.y; Bs[lk+2][r]=c.z; Bs[lk+3][r]=c.w;
    }
    __syncthreads();
    #pragma unroll
    for (int kk=0;kk<32;kk++){
      float4 av = *(const float4*)&As[kk][ty*4];
      float4 bv = *(const float4*)&Bs[kk][tx*4];
      float a4[4] = {av.x,av.y,av.z,av.w};
      float b4[4] = {bv.x,bv.y,bv.z,bv.w};
      #pragma unroll
      for (int r=0;r<4;r++)
        #pragma unroll
        for (int c2=0;c2<4;c2++) acc[r][c2] += a4[r]*b4[c2];
    }
    __syncthreads();
  }
  float* dbase = dist + (size_t)b * N_ * N_;
  #pragma unroll
  for (int r=0;r<4;r++){
    int i = bi*64 + ty*4 + r;
    float si = sq[b*N_ + i];
    #pragma unroll
    for (int c2=0;c2<4;c2++){
      int j = bj*64 + tx*4 + c2;
      float d2 = si + sq[b*N_ + j] - 2.f*acc[r][c2];
      dbase[(size_t)i*N_ + j] = sqrtf(fmaxf(d2, 0.f)) * 0.0625f;
    }
  }
}

// ---------------- per-row 5 smallest -> density (+noise), row max ----------------
__global__ __launch_bounds__(256) void k_top5(const float* __restrict__ dist, float* __restrict__ density,
                                              float* __restrict__ rowmax){
  int row = blockIdx.x * 4 + (threadIdx.x >> 6);
  int l = threadIdx.x & 63;
  const float* p = dist + (size_t)row * N_;
  float t[5] = {1e30f,1e30f,1e30f,1e30f,1e30f};
  float mx = 0.f;
  #pragma unroll
  for (int q2=0;q2<16;q2++){
    float v = p[l + 64*q2];
    mx = fmaxf(mx, v);
    if (v < t[4]){
      t[4] = v;
      #pragma unroll
      for (int a=4;a>0;a--) if (t[a] < t[a-1]) { float tmp=t[a]; t[a]=t[a-1]; t[a-1]=tmp; }
    }
  }
  #pragma unroll
  for (int m=32;m;m>>=1) mx = fmaxf(mx, __shfl_xor(mx, m));
  // extract 5 global smallest across the wave (each lane holds sorted 5)
  float sumsq = 0.f;
  int hi = 0;
  #pragma unroll
  for (int a=0;a<5;a++){
    float head = (hi==0)?t[0]:(hi==1)?t[1]:(hi==2)?t[2]:(hi==3)?t[3]:(hi==4)?t[4]:1e30f;
    float m = head;
    #pragma unroll
    for (int mm=32;mm;mm>>=1) m = fminf(m, __shfl_xor(m, mm));
    sumsq += m*m;
    unsigned long long ball = __ballot(head == m);
    if (l == (__ffsll(ball) - 1)) hi++;
  }
  if (l == 0){
    float msq = sumsq / 5.0f;
    density[row] = expf(-msq) + tf_noise((unsigned)row) * 1e-6f;
    rowmax[row] = mx;
  }
}

__global__ __launch_bounds__(256) void k_bmax(const float* __restrict__ rowmax, float* __restrict__ bmax){
  int b = blockIdx.x; int t = threadIdx.x;
  float m = fmaxf(fmaxf(rowmax[b*N_+t], rowmax[b*N_+t+256]),
                  fmaxf(rowmax[b*N_+t+512], rowmax[b*N_+t+768]));
  __shared__ float s[256];
  s[t]=m; __syncthreads();
  for (int d=128; d; d>>=1){ if (t<d) s[t]=fmaxf(s[t],s[t+d]); __syncthreads(); }
  if (t==0) bmax[b]=s[0];
}

// ---------------- d_ind = min dist over higher-density peers; score ----------------
__global__ __launch_bounds__(256) void k_dind(const float* __restrict__ dist, const float* __restrict__ density,
                                              const float* __restrict__ bmax, float* __restrict__ score){
  int row = blockIdx.x * 4 + (threadIdx.x >> 6);
  int b = row >> 10;
  int l = threadIdx.x & 63;
  const float* p = dist + (size_t)row * N_;
  const float* db = density + b*N_;
  float di = density[row];
  float m = bmax[b];
  #pragma unroll
  for (int q2=0;q2<16;q2++){
    int j = l + 64*q2;
    float dj = db[j];
    if (dj > di) m = fminf(m, p[j]);
  }
  #pragma unroll
  for (int mm=32;mm;mm>>=1) m = fminf(m, __shfl_xor(m, mm));
  if (l==0) score[row] = m * di;
}

// ---------------- stable top-256 via full bitonic sort (desc score, asc idx) ----------------
__global__ __launch_bounds__(1024) void k_top256(const float* __restrict__ score, int* __restrict__ idxdown){
  int b = blockIdx.x; int t = threadIdx.x;
  __shared__ float sv[1024];
  __shared__ int si[1024];
  sv[t] = score[b*N_ + t]; si[t] = t;
  __syncthreads();
  for (int k = 2; k <= 1024; k <<= 1){
    for (int j = k >> 1; j > 0; j >>= 1){
      int l = t ^ j;
      if (l > t){
        bool up = ((t & k) == 0);
        float a = sv[t], b2 = sv[l]; int ai = si[t], bi2 = si[l];
        bool prec = (a > b2) || (a == b2 && ai < bi2); // a precedes b in final order
        bool dosw = up ? (!prec) : prec;
        if (dosw){ sv[t]=b2; sv[l]=a; si[t]=bi2; si[l]=ai; }
      }
      __syncthreads();
    }
  }
  if (t < CN_) idxdown[b*CN_ + t] = si[t];
}

// ---------------- assign tokens to nearest center (first-occurrence argmin) ----------------
__global__ __launch_bounds__(256) void k_assign(const float* __restrict__ dist, const int* __restrict__ idxdown,
                                                int* __restrict__ idxclu){
  int b = blockIdx.y;
  int j = blockIdx.x*256 + threadIdx.x;
  __shared__ int cen[256];
  cen[threadIdx.x] = idxdown[b*CN_ + threadIdx.x];
  __syncthreads();
  const float* dbase = dist + (size_t)b*N_*N_;
  float best = 1e30f; int bk = 0;
  for (int k=0;k<CN_;k++){
    float d = dbase[(size_t)cen[k]*N_ + j];
    if (d < best){ best = d; bk = k; }
  }
  idxclu[b*N_ + j] = bk;
}

__global__ void k_setcenters(const int* __restrict__ idxdown, int* __restrict__ idxclu){
  int b = blockIdx.x; int t = threadIdx.x;
  idxclu[b*N_ + idxdown[b*CN_ + t]] = t;
}

__global__ void k_zero(int* p, int n){ int i = blockIdx.x*256+threadIdx.x; if (i<n) p[i]=0; }

__global__ void k_hist(const int* __restrict__ idxclu, int* __restrict__ cnt){
  int i = blockIdx.x*256 + threadIdx.x;
  int b = i >> 10;
  atomicAdd(&cnt[b*CN_ + idxclu[i]], 1);
}

__global__ __launch_bounds__(256) void k_scan(const int* __restrict__ cnt, int* __restrict__ off,
                                              int* __restrict__ cur){
  int b = blockIdx.x; int t = threadIdx.x;
  __shared__ int s[256];
  int mine = cnt[b*CN_ + t];
  s[t] = mine;
  __syncthreads();
  for (int d = 1; d < 256; d <<= 1){
    int v = 0;
    if (t >= d) v = s[t - d];
    __syncthreads();
    if (t >= d) s[t] += v;
    __syncthreads();
  }
  int excl = s[t] - mine;
  off[b*CN_ + t] = excl;
  cur[b*CN_ + t] = excl;
}

__global__ void k_scatter(const int* __restrict__ idxclu, int* __restrict__ cur, int* __restrict__ members){
  int i = blockIdx.x*256 + threadIdx.x;
  int b = i >> 10; int tok = i & 1023;
  int c = idxclu[i];
  int p = atomicAdd(&cur[b*CN_ + c], 1);
  members[b*N_ + p] = tok;
}

// ---------------- Y = X @ W^T (+bias), X:(8192,256) W:(256,256) ----------------
__global__ __launch_bounds__(256) void k_gemm_nt(const float* __restrict__ X, const float* __restrict__ W,
                                                 const float* __restrict__ bias, float* __restrict__ Y){
  __shared__ __align__(16) float As[32][68];
  __shared__ __align__(16) float Bs[32][68];
  int bx = blockIdx.x;   // output-col tile (4)
  int by = blockIdx.y;   // row tile (128)
  int tid = threadIdx.x;
  int tx = tid & 15, ty = tid >> 4;
  int lrow = tid >> 3, lk = (tid & 7)*4;
  float acc[4][4] = {};
  for (int k0=0;k0<256;k0+=32){
    #pragma unroll
    for (int rr=0;rr<2;rr++){
      int r = rr*32 + lrow;
      float4 a = *(const float4*)(X + (size_t)(by*64 + r)*256 + k0 + lk);
      As[lk+0][r]=a.x; As[lk+1][r]=a.y; As[lk+2][r]=a.z; As[lk+3][r]=a.w;
      float4 c = *(const float4*)(W + (size_t)(bx*64 + r)*256 + k0 + lk);
      Bs[lk+0][r]=c.x; Bs[lk+1][r]=c.y; Bs[lk+2][r]=c.z; Bs[lk+3][r]=c.w;
    }
    __syncthreads();
    #pragma unroll
    for (int kk=0;kk<32;kk++){
      float4 av = *(const float4*)&As[kk][ty*4];
      float4 bv = *(const float4*)&Bs[kk][tx*4];
      float a4[4] = {av.x,av.y,av.z,av.w};
      float b4[4] = {bv.x,bv.y,bv.z,bv.w};
      #pragma unroll
      for (int r=0;r<4;r++)
        #pragma unroll
        for (int c2=0;c2<4;c2++) acc[r][c2] += a4[r]*b4[c2];
    }
    __syncthreads();
  }
  #pragma unroll
  for (int r=0;r<4;r++){
    int m = by*64 + ty*4 + r;
    #pragma unroll
    for (int c2=0;c2<4;c2++){
      int o = bx*64 + tx*4 + c2;
      float v = acc[r][c2];
      if (bias) v += bias[o];
      Y[(size_t)m*256 + o] = v;
    }
  }
}

__global__ void k_vsum(const float* __restrict__ v, float* __restrict__ vsum){
  int b = blockIdx.x; int c = threadIdx.x;
  float s = 0.f;
  for (int i=0;i<N_;i++) s += v[((size_t)b*N_ + i)*C_ + c];
  vsum[b*C_ + c] = s;
}

// ---------------- cluster-sparse attention ----------------
__global__ __launch_bounds__(256) void k_attn(const float* __restrict__ q, const float* __restrict__ kmat,
                                              const float* __restrict__ v, const float* __restrict__ vsum,
                                              const int* __restrict__ idxclu, const int* __restrict__ off,
                                              const int* __restrict__ cnt, const int* __restrict__ members,
                                              float* __restrict__ att){
  int bi = blockIdx.x;            // b*N + i
  int b = bi >> 10;
  int h = threadIdx.x >> 6, l = threadIdx.x & 63;
  int c = idxclu[bi];
  int o = off[b*CN_ + c], m = cnt[b*CN_ + c];
  int ch = h*64 + l;
  float qv = q[(size_t)bi*C_ + ch];
  float acc = 0.f, den = 0.f;
  const int* mem = members + b*N_ + o;
  for (int t=0;t<m;t++){
    int j = mem[t];
    size_t base = ((size_t)(b*N_ + j))*C_ + ch;
    float p = qv * kmat[base];
    #pragma unroll
    for (int mm=32;mm;mm>>=1) p += __shfl_xor(p, mm);
    float s = p * 0.125f;
    float e = (s == 0.0f) ? 0.0f : expf(s);   // faithful: attn==0 -> -1e9 -> exp=0
    den += e;
    acc += e * v[base];
  }
  float outv = (acc + (EPS_/1024.0f) * vsum[b*C_ + ch]) / (den + EPS_);
  att[(size_t)bi*C_ + ch] = outv;
}

extern "C" void kernel_launch(void* const* d_in, const int* in_sizes, int n_in,
                              void* d_out, int out_size, void* d_ws, size_t ws_size,
                              hipStream_t stream){
  const float* x  = (const float*)d_in[0];
  const float* Wq = (const float*)d_in[1];
  const float* Wk = (const float*)d_in[2];
  const float* Wv = (const float*)d_in[3];
  const float* Wp = (const float*)d_in[4];
  const float* bp = (const float*)d_in[5];
  float* out = (float*)d_out;

  float* ws = (float*)d_ws;
  float* dist    = ws;                                  // 8*1024*1024
  float* q       = dist + (size_t)B_*N_*N_;             // 2M
  float* kk      = q    + (size_t)B_*N_*C_;
  float* v       = kk   + (size_t)B_*N_*C_;
  float* att     = v    + (size_t)B_*N_*C_;
  float* sq      = att  + (size_t)B_*N_*C_;             // 8192
  float* rowmax  = sq + B_*N_;
  float* bmax    = rowmax + B_*N_;                      // 8
  float* density = bmax + 16;
  float* score   = density + B_*N_;
  float* vsum    = score + B_*N_;                       // 2048
  int* idxdown   = (int*)(vsum + B_*C_);                // 2048
  int* idxclu    = idxdown + B_*CN_;                    // 8192
  int* cnt       = idxclu + B_*N_;                      // 2048
  int* cur       = cnt + B_*CN_;                        // 2048
  int* off       = cur + B_*CN_;                        // 2048
  int* members   = off + B_*CN_;                        // 8192

  k_zero<<<16,256,0,stream>>>(cnt, 4096);               // cnt + cur
  k_sq<<<B_*N_/4,256,0,stream>>>(x, sq);
  k_dist<<<dim3(16,16,8),256,0,stream>>>(x, sq, dist);
  k_top5<<<B_*N_/4,256,0,stream>>>(dist, density, rowmax);
  k_bmax<<<8,256,0,stream>>>(rowmax, bmax);
  k_dind<<<B_*N_/4,256,0,stream>>>(dist, density, bmax, score);
  k_top256<<<8,1024,0,stream>>>(score, idxdown);
  k_assign<<<dim3(4,8),256,0,stream>>>(dist, idxdown, idxclu);
  k_setcenters<<<8,256,0,stream>>>(idxdown, idxclu);
  k_hist<<<32,256,0,stream>>>(idxclu, cnt);
  k_scan<<<8,256,0,stream>>>(cnt, off, cur);
  k_scatter<<<32,256,0,stream>>>(idxclu, cur, members);
  k_gemm_nt<<<dim3(4,128),256,0,stream>>>(x, Wq, nullptr, q);
  k_gemm_nt<<<dim3(4,128),256,0,stream>>>(x, Wk, nullptr, kk);
  k_gemm_nt<<<dim3(4,128),256,0,stream>>>(x, Wv, nullptr, v);
  k_vsum<<<8,256,0,stream>>>(v, vsum);
  k_attn<<<B_*N_,256,0,stream>>>(q, kk, v, vsum, idxclu, off, cnt, members, att);
  k_gemm_nt<<<dim3(4,128),256,0,stream>>>(att, Wp, bp, out);
}

// Round 2
// 337.460 us; speedup vs baseline: 1.0819x; 1.0819x over previous
//
#include <hip/hip_runtime.h>
#include <math.h>

#define B_ 8
#define N_ 1024
#define C_ 256
#define H_ 4
#define D_ 64
#define CN_ 256
#define EPS_ 1e-6f

// ---------------- threefry2x32 (JAX-compatible) ----------------
__device__ __forceinline__ unsigned rotl32(unsigned x, int r){ return (x<<r)|(x>>(32-r)); }

__device__ float tf_noise(unsigned gid){
  unsigned c0 = (gid >= 4096u) ? gid - 4096u : gid;
  unsigned c1 = c0 + 4096u;
  const unsigned k0 = 0u, k1 = 42u;
  const unsigned ks2 = k0 ^ k1 ^ 0x1BD11BDAu;
  unsigned x0 = c0 + k0, x1 = c1 + k1;
  const int R0[4] = {13,15,26,6};
  const int R1[4] = {17,29,16,24};
  #pragma unroll
  for (int i=0;i<4;i++){ x0 += x1; x1 = rotl32(x1,R0[i]); x1 ^= x0; }
  x0 += k1; x1 += ks2 + 1u;
  #pragma unroll
  for (int i=0;i<4;i++){ x0 += x1; x1 = rotl32(x1,R1[i]); x1 ^= x0; }
  x0 += ks2; x1 += k0 + 2u;
  #pragma unroll
  for (int i=0;i<4;i++){ x0 += x1; x1 = rotl32(x1,R0[i]); x1 ^= x0; }
  x0 += k0; x1 += k1 + 3u;
  #pragma unroll
  for (int i=0;i<4;i++){ x0 += x1; x1 = rotl32(x1,R1[i]); x1 ^= x0; }
  x0 += k1; x1 += ks2 + 4u;
  #pragma unroll
  for (int i=0;i<4;i++){ x0 += x1; x1 = rotl32(x1,R0[i]); x1 ^= x0; }
  x0 += ks2; x1 += k0 + 5u;
  unsigned bits = (gid >= 4096u) ? x1 : x0;
  return __uint_as_float(0x3F800000u | (bits >> 9)) - 1.0f;
}

// ---------------- sq of rows ----------------
__global__ __launch_bounds__(256) void k_sq(const float* __restrict__ x, float* __restrict__ sq){
  int row = blockIdx.x * 4 + (threadIdx.x >> 6);
  int l = threadIdx.x & 63;
  const float* p = x + (size_t)row * C_;
  float s = 0.f;
  #pragma unroll
  for (int t=0;t<4;t++){ float v = p[l + 64*t]; s += v*v; }
  #pragma unroll
  for (int m=32;m;m>>=1) s += __shfl_xor(s, m);
  if (l==0) sq[row] = s;
}

// ---------------- dist GEMM: 128x128 tile, 8x8 microtile, fp32 ----------------
__global__ __launch_bounds__(256) void k_dist2(const float* __restrict__ x, const float* __restrict__ sq,
                                               float* __restrict__ dist){
  int b = blockIdx.z, bi = blockIdx.y, bj = blockIdx.x;
  const float* xb = x + (size_t)b * N_ * C_;
  __shared__ float As[16][132];
  __shared__ float Bs[16][132];
  int tid = threadIdx.x;
  int tx = tid & 15, ty = tid >> 4;
  float acc[8][8] = {};
  for (int k0=0;k0<C_;k0+=16){
    float4 ra[2], rb[2];
    #pragma unroll
    for (int f=0;f<2;f++){
      int idx = tid*2+f;
      int row = idx>>2, kq = idx&3;
      ra[f] = *(const float4*)(xb + (size_t)(bi*128+row)*C_ + k0 + kq*4);
      rb[f] = *(const float4*)(xb + (size_t)(bj*128+row)*C_ + k0 + kq*4);
    }
    __syncthreads();
    #pragma unroll
    for (int f=0;f<2;f++){
      int idx = tid*2+f;
      int row = idx>>2, kq = idx&3;
      As[kq*4+0][row]=ra[f].x; As[kq*4+1][row]=ra[f].y; As[kq*4+2][row]=ra[f].z; As[kq*4+3][row]=ra[f].w;
      Bs[kq*4+0][row]=rb[f].x; Bs[kq*4+1][row]=rb[f].y; Bs[kq*4+2][row]=rb[f].z; Bs[kq*4+3][row]=rb[f].w;
    }
    __syncthreads();
    #pragma unroll
    for (int kk=0;kk<16;kk++){
      float4 a0 = *(const float4*)&As[kk][ty*8];
      float4 a1 = *(const float4*)&As[kk][ty*8+4];
      float4 b0 = *(const float4*)&Bs[kk][tx*8];
      float4 b1 = *(const float4*)&Bs[kk][tx*8+4];
      float av[8]={a0.x,a0.y,a0.z,a0.w,a1.x,a1.y,a1.z,a1.w};
      float bv[8]={b0.x,b0.y,b0.z,b0.w,b1.x,b1.y,b1.z,b1.w};
      #pragma unroll
      for (int r=0;r<8;r++)
        #pragma unroll
        for (int c=0;c<8;c++) acc[r][c] += av[r]*bv[c];
    }
  }
  int ibase = bi*128 + ty*8, jbase = bj*128 + tx*8;
  float sj[8];
  #pragma unroll
  for (int c=0;c<8;c++) sj[c] = sq[b*N_ + jbase + c];
  float* dbase = dist + (size_t)b * N_ * N_;
  #pragma unroll
  for (int r=0;r<8;r++){
    int i = ibase + r;
    float si = sq[b*N_ + i];
    float o[8];
    #pragma unroll
    for (int c=0;c<8;c++){
      float d2 = si + sj[c] - 2.f*acc[r][c];
      o[c] = sqrtf(fmaxf(d2, 0.f)) * 0.0625f;
    }
    *(float4*)(dbase + (size_t)i*N_ + jbase)     = make_float4(o[0],o[1],o[2],o[3]);
    *(float4*)(dbase + (size_t)i*N_ + jbase + 4) = make_float4(o[4],o[5],o[6],o[7]);
  }
}

// ---------------- projection GEMM: Y = X @ W^T (+bias), same tile ----------------
__global__ __launch_bounds__(256) void k_gemm2(const float* __restrict__ X,
    const float* __restrict__ W0, const float* __restrict__ W1, const float* __restrict__ W2,
    const float* __restrict__ bias,
    float* __restrict__ Y0, float* __restrict__ Y1, float* __restrict__ Y2){
  const float* W = (blockIdx.z==0)?W0:(blockIdx.z==1)?W1:W2;
  float* Y = (blockIdx.z==0)?Y0:(blockIdx.z==1)?Y1:Y2;
  int bi = blockIdx.y, bj = blockIdx.x;
  __shared__ float As[16][132];
  __shared__ float Bs[16][132];
  int tid = threadIdx.x;
  int tx = tid & 15, ty = tid >> 4;
  float acc[8][8] = {};
  for (int k0=0;k0<C_;k0+=16){
    float4 ra[2], rb[2];
    #pragma unroll
    for (int f=0;f<2;f++){
      int idx = tid*2+f;
      int row = idx>>2, kq = idx&3;
      ra[f] = *(const float4*)(X + (size_t)(bi*128+row)*C_ + k0 + kq*4);
      rb[f] = *(const float4*)(W + (size_t)(bj*128+row)*C_ + k0 + kq*4);
    }
    __syncthreads();
    #pragma unroll
    for (int f=0;f<2;f++){
      int idx = tid*2+f;
      int row = idx>>2, kq = idx&3;
      As[kq*4+0][row]=ra[f].x; As[kq*4+1][row]=ra[f].y; As[kq*4+2][row]=ra[f].z; As[kq*4+3][row]=ra[f].w;
      Bs[kq*4+0][row]=rb[f].x; Bs[kq*4+1][row]=rb[f].y; Bs[kq*4+2][row]=rb[f].z; Bs[kq*4+3][row]=rb[f].w;
    }
    __syncthreads();
    #pragma unroll
    for (int kk=0;kk<16;kk++){
      float4 a0 = *(const float4*)&As[kk][ty*8];
      float4 a1 = *(const float4*)&As[kk][ty*8+4];
      float4 b0 = *(const float4*)&Bs[kk][tx*8];
      float4 b1 = *(const float4*)&Bs[kk][tx*8+4];
      float av[8]={a0.x,a0.y,a0.z,a0.w,a1.x,a1.y,a1.z,a1.w};
      float bv[8]={b0.x,b0.y,b0.z,b0.w,b1.x,b1.y,b1.z,b1.w};
      #pragma unroll
      for (int r=0;r<8;r++)
        #pragma unroll
        for (int c=0;c<8;c++) acc[r][c] += av[r]*bv[c];
    }
  }
  int jbase = bj*128 + tx*8;
  float bs[8];
  #pragma unroll
  for (int c=0;c<8;c++) bs[c] = bias ? bias[jbase+c] : 0.f;
  #pragma unroll
  for (int r=0;r<8;r++){
    int m = bi*128 + ty*8 + r;
    float o[8];
    #pragma unroll
    for (int c=0;c<8;c++) o[c] = acc[r][c] + bs[c];
    *(float4*)(Y + (size_t)m*C_ + jbase)     = make_float4(o[0],o[1],o[2],o[3]);
    *(float4*)(Y + (size_t)m*C_ + jbase + 4) = make_float4(o[4],o[5],o[6],o[7]);
  }
}

// ---------------- per-row 5 smallest -> density (+noise), row max ----------------
__global__ __launch_bounds__(256) void k_top5(const float* __restrict__ dist, float* __restrict__ density,
                                              float* __restrict__ rowmax){
  int row = blockIdx.x * 4 + (threadIdx.x >> 6);
  int l = threadIdx.x & 63;
  const float* p = dist + (size_t)row * N_;
  float t[5] = {1e30f,1e30f,1e30f,1e30f,1e30f};
  float mx = 0.f;
  #pragma unroll
  for (int q2=0;q2<16;q2++){
    float v = p[l + 64*q2];
    mx = fmaxf(mx, v);
    if (v < t[4]){
      t[4] = v;
      #pragma unroll
      for (int a=4;a>0;a--) if (t[a] < t[a-1]) { float tmp=t[a]; t[a]=t[a-1]; t[a-1]=tmp; }
    }
  }
  #pragma unroll
  for (int m=32;m;m>>=1) mx = fmaxf(mx, __shfl_xor(mx, m));
  float sumsq = 0.f;
  int hi = 0;
  #pragma unroll
  for (int a=0;a<5;a++){
    float head = (hi==0)?t[0]:(hi==1)?t[1]:(hi==2)?t[2]:(hi==3)?t[3]:(hi==4)?t[4]:1e30f;
    float m = head;
    #pragma unroll
    for (int mm=32;mm;mm>>=1) m = fminf(m, __shfl_xor(m, mm));
    sumsq += m*m;
    unsigned long long ball = __ballot(head == m);
    if (l == (__ffsll(ball) - 1)) hi++;
  }
  if (l == 0){
    float msq = sumsq / 5.0f;
    density[row] = expf(-msq) + tf_noise((unsigned)row) * 1e-6f;
    rowmax[row] = mx;
  }
}

__global__ __launch_bounds__(256) void k_bmax(const float* __restrict__ rowmax, float* __restrict__ bmax){
  int b = blockIdx.x; int t = threadIdx.x;
  float m = fmaxf(fmaxf(rowmax[b*N_+t], rowmax[b*N_+t+256]),
                  fmaxf(rowmax[b*N_+t+512], rowmax[b*N_+t+768]));
  __shared__ float s[256];
  s[t]=m; __syncthreads();
  for (int d=128; d; d>>=1){ if (t<d) s[t]=fmaxf(s[t],s[t+d]); __syncthreads(); }
  if (t==0) bmax[b]=s[0];
}

// ---------------- d_ind = min dist over higher-density peers; score ----------------
__global__ __launch_bounds__(256) void k_dind(const float* __restrict__ dist, const float* __restrict__ density,
                                              const float* __restrict__ bmax, float* __restrict__ score){
  int row = blockIdx.x * 4 + (threadIdx.x >> 6);
  int b = row >> 10;
  int l = threadIdx.x & 63;
  const float* p = dist + (size_t)row * N_;
  const float* db = density + b*N_;
  float di = density[row];
  float m = bmax[b];
  #pragma unroll
  for (int q2=0;q2<16;q2++){
    int j = l + 64*q2;
    float dj = db[j];
    if (dj > di) m = fminf(m, p[j]);
  }
  #pragma unroll
  for (int mm=32;mm;mm>>=1) m = fminf(m, __shfl_xor(m, mm));
  if (l==0) score[row] = m * di;
}

// ---------------- stable top-256 via full bitonic sort (desc score, asc idx) ----------------
__global__ __launch_bounds__(1024) void k_top256(const float* __restrict__ score, int* __restrict__ idxdown){
  int b = blockIdx.x; int t = threadIdx.x;
  __shared__ float sv[1024];
  __shared__ int si[1024];
  sv[t] = score[b*N_ + t]; si[t] = t;
  __syncthreads();
  for (int k = 2; k <= 1024; k <<= 1){
    for (int j = k >> 1; j > 0; j >>= 1){
      int l = t ^ j;
      if (l > t){
        bool up = ((t & k) == 0);
        float a = sv[t], b2 = sv[l]; int ai = si[t], bi2 = si[l];
        bool prec = (a > b2) || (a == b2 && ai < bi2);
        bool dosw = up ? (!prec) : prec;
        if (dosw){ sv[t]=b2; sv[l]=a; si[t]=bi2; si[l]=ai; }
      }
      __syncthreads();
    }
  }
  if (t < CN_) idxdown[b*CN_ + t] = si[t];
}

// ---------------- assign tokens to nearest center (first-occurrence argmin) ----------------
__global__ __launch_bounds__(256) void k_assign(const float* __restrict__ dist, const int* __restrict__ idxdown,
                                                int* __restrict__ idxclu){
  int b = blockIdx.y;
  int j = blockIdx.x*256 + threadIdx.x;
  __shared__ int cen[256];
  cen[threadIdx.x] = idxdown[b*CN_ + threadIdx.x];
  __syncthreads();
  const float* dbase = dist + (size_t)b*N_*N_;
  float best = 1e30f; int bk = 0;
  for (int k=0;k<CN_;k++){
    float d = dbase[(size_t)cen[k]*N_ + j];
    if (d < best){ best = d; bk = k; }
  }
  idxclu[b*N_ + j] = bk;
}

__global__ void k_setcenters(const int* __restrict__ idxdown, int* __restrict__ idxclu){
  int b = blockIdx.x; int t = threadIdx.x;
  idxclu[b*N_ + idxdown[b*CN_ + t]] = t;
}

// ---------------- hist + scan + scatter in one LDS-resident kernel ----------------
__global__ __launch_bounds__(256) void k_build(const int* __restrict__ idxclu, int* __restrict__ off,
                                               int* __restrict__ cnt, int* __restrict__ members){
  int b = blockIdx.x; int t = threadIdx.x;
  __shared__ int sc[256], so[256];
  sc[t] = 0;
  __syncthreads();
  int cl[4];
  #pragma unroll
  for (int i=0;i<4;i++){
    cl[i] = idxclu[b*N_ + i*256 + t];
    atomicAdd(&sc[cl[i]], 1);
  }
  __syncthreads();
  int mine = sc[t];
  so[t] = mine;
  __syncthreads();
  for (int d=1; d<256; d<<=1){
    int v2 = 0;
    if (t>=d) v2 = so[t-d];
    __syncthreads();
    if (t>=d) so[t] += v2;
    __syncthreads();
  }
  int excl = so[t] - mine;
  off[b*CN_+t] = excl;
  cnt[b*CN_+t] = mine;
  sc[t] = excl;
  __syncthreads();
  #pragma unroll
  for (int i=0;i<4;i++){
    int p = atomicAdd(&sc[cl[i]], 1);
    members[b*N_ + p] = i*256 + t;
  }
}

// ---------------- vsum: two-phase parallel ----------------
__global__ __launch_bounds__(256) void k_vsum1(const float* __restrict__ v, float* __restrict__ vsp){
  int p = blockIdx.x;           // b*16 + s
  int b = p >> 4, s = p & 15;
  int c = threadIdx.x;
  float acc = 0.f;
  const float* base = v + ((size_t)b*N_ + s*64)*C_ + c;
  #pragma unroll 8
  for (int i=0;i<64;i++) acc += base[(size_t)i*C_];
  vsp[(size_t)p*C_ + c] = acc;
}

__global__ __launch_bounds__(256) void k_vsum2(const float* __restrict__ vsp, float* __restrict__ vsum){
  int b = blockIdx.x; int c = threadIdx.x;
  float s = 0.f;
  #pragma unroll
  for (int i=0;i<16;i++) s += vsp[((size_t)b*16 + i)*C_ + c];
  vsum[b*C_ + c] = s;
}

// ---------------- cluster-sparse attention ----------------
__global__ __launch_bounds__(256) void k_attn(const float* __restrict__ q, const float* __restrict__ kmat,
                                              const float* __restrict__ v, const float* __restrict__ vsum,
                                              const int* __restrict__ idxclu, const int* __restrict__ off,
                                              const int* __restrict__ cnt, const int* __restrict__ members,
                                              float* __restrict__ att){
  int bi = blockIdx.x;            // b*N + i
  int b = bi >> 10;
  int h = threadIdx.x >> 6, l = threadIdx.x & 63;
  int c = idxclu[bi];
  int o = off[b*CN_ + c], m = cnt[b*CN_ + c];
  int ch = h*64 + l;
  float qv = q[(size_t)bi*C_ + ch];
  float acc = 0.f, den = 0.f;
  const int* mem = members + b*N_ + o;
  for (int t=0;t<m;t++){
    int j = mem[t];
    size_t base = ((size_t)(b*N_ + j))*C_ + ch;
    float p = qv * kmat[base];
    #pragma unroll
    for (int mm=32;mm;mm>>=1) p += __shfl_xor(p, mm);
    float s = p * 0.125f;
    float e = (s == 0.0f) ? 0.0f : expf(s);
    den += e;
    acc += e * v[base];
  }
  float outv = (acc + (EPS_/1024.0f) * vsum[b*C_ + ch]) / (den + EPS_);
  att[(size_t)bi*C_ + ch] = outv;
}

extern "C" void kernel_launch(void* const* d_in, const int* in_sizes, int n_in,
                              void* d_out, int out_size, void* d_ws, size_t ws_size,
                              hipStream_t stream){
  const float* x  = (const float*)d_in[0];
  const float* Wq = (const float*)d_in[1];
  const float* Wk = (const float*)d_in[2];
  const float* Wv = (const float*)d_in[3];
  const float* Wp = (const float*)d_in[4];
  const float* bp = (const float*)d_in[5];
  float* out = (float*)d_out;

  float* ws = (float*)d_ws;
  float* dist    = ws;                                  // 8M floats
  float* q       = dist + (size_t)B_*N_*N_;             // 2M
  float* kk      = q    + (size_t)B_*N_*C_;
  float* v       = kk   + (size_t)B_*N_*C_;
  float* att     = v    + (size_t)B_*N_*C_;
  float* vsp     = att  + (size_t)B_*N_*C_;             // 128*256
  float* vsum    = vsp + 128*C_;                        // 2048
  float* sq      = vsum + B_*C_;                        // 8192
  float* rowmax  = sq + B_*N_;
  float* bmax    = rowmax + B_*N_;                      // 16
  float* density = bmax + 16;
  float* score   = density + B_*N_;
  int* idxdown   = (int*)(score + B_*N_);               // 2048
  int* idxclu    = idxdown + B_*CN_;                    // 8192
  int* cnt       = idxclu + B_*N_;                      // 2048
  int* off       = cnt + B_*CN_;                        // 2048
  int* members   = off + B_*CN_;                        // 8192

  k_sq<<<B_*N_/4,256,0,stream>>>(x, sq);
  k_dist2<<<dim3(8,8,8),256,0,stream>>>(x, sq, dist);
  k_top5<<<B_*N_/4,256,0,stream>>>(dist, density, rowmax);
  k_bmax<<<8,256,0,stream>>>(rowmax, bmax);
  k_dind<<<B_*N_/4,256,0,stream>>>(dist, density, bmax, score);
  k_top256<<<8,1024,0,stream>>>(score, idxdown);
  k_assign<<<dim3(4,8),256,0,stream>>>(dist, idxdown, idxclu);
  k_setcenters<<<8,256,0,stream>>>(idxdown, idxclu);
  k_build<<<8,256,0,stream>>>(idxclu, off, cnt, members);
  k_gemm2<<<dim3(2,64,3),256,0,stream>>>(x, Wq, Wk, Wv, nullptr, q, kk, v);
  k_vsum1<<<128,256,0,stream>>>(v, vsp);
  k_vsum2<<<8,256,0,stream>>>(vsp, vsum);
  k_attn<<<B_*N_,256,0,stream>>>(q, kk, v, vsum, idxclu, off, cnt, members, att);
  k_gemm2<<<dim3(2,64,1),256,0,stream>>>(att, Wp, Wp, Wp, bp, out, out, out);
}